// Round 3
// baseline (528.521 us; speedup 1.0000x reference)
//
#include <hip/hip_runtime.h>
#include <cstdint>
#include <cstddef>

// Problem dims (fixed by setup_inputs): B=4, S=2048, I=4096, O=4096
#define DIM_M 8192   // B*S
#define DIM_N 4096   // O
#define DIM_K 4096   // I

// GEMM tiling: 256x256 tile, BK=32, 4-deep LDS ring, 1 barrier/tile,
// cross-tile software-pipelined LDS reads (counted lgkmcnt).
#define BM 256
#define BN 256
#define BK 32
#define NT (DIM_K / BK)   // 128 K-tiles

typedef __bf16 bf16x8 __attribute__((ext_vector_type(8)));
typedef float fvec4 __attribute__((ext_vector_type(4)));
typedef int   ivec4 __attribute__((ext_vector_type(4)));
typedef unsigned int uvec4 __attribute__((ext_vector_type(4)));

__device__ __constant__ float NF4_TAB[16] = {
    -1.0f, -0.6961928009986877f, -0.5250730514526367f, -0.39491748809814453f,
    -0.28444138169288635f, -0.18477343022823334f, -0.09105003625154495f, 0.0f,
    0.07958029955625534f, 0.16093020141124725f, 0.24611230194568634f,
    0.33791524171829224f, 0.44070982933044434f, 0.5626170039176941f,
    0.7229568362236023f, 1.0f};

// float -> bf16 bits, round-to-nearest-even (finite inputs only)
__device__ inline unsigned short f2bf(float f) {
    unsigned int u = __builtin_bit_cast(unsigned int, f);
    u += 0x7fffu + ((u >> 16) & 1u);
    return (unsigned short)(u >> 16);
}

// ---------------- fused prep: x fp32->bf16  +  NF4 double-dequant ----------------
// CHANGE this round: plain (cacheable) loads instead of nontemporal.  Wall-minus-
// gemm has been ~225 us across 3 rounds vs a ~46 us streaming roofline; the only
// deviation from the measured 6.29 TB/s copy pattern (m13) was the nt loads.
// This is a hypothesis test with its own dispatch, separately attributable.
__global__ void prep_kernel(const float* __restrict__ x, unsigned short* __restrict__ xb,
                            const int* __restrict__ codes,
                            const int* __restrict__ am_codes,
                            const float* __restrict__ am_scale,
                            const float* __restrict__ am_off,
                            unsigned short* __restrict__ wb,
                            int xcv_blocks) {
    if ((int)blockIdx.x < xcv_blocks) {
        size_t base = ((size_t)blockIdx.x * blockDim.x + threadIdx.x) * 8;
        fvec4 a = *(const fvec4*)(x + base);
        fvec4 b = *(const fvec4*)(x + base + 4);
        unsigned short r[8];
        r[0] = f2bf(a.x); r[1] = f2bf(a.y); r[2] = f2bf(a.z); r[3] = f2bf(a.w);
        r[4] = f2bf(b.x); r[5] = f2bf(b.y); r[6] = f2bf(b.z); r[7] = f2bf(b.w);
        *(uvec4*)(xb + base) = *(const uvec4*)r;
    } else {
        __shared__ float nf4[16];
        if (threadIdx.x < 16) nf4[threadIdx.x] = NF4_TAB[threadIdx.x];
        __syncthreads();
        size_t base = ((size_t)(blockIdx.x - xcv_blocks) * blockDim.x + threadIdx.x) * 8;
        int blk = (int)(base >> 6);
        float absmax = (float)am_codes[blk] * (1.0f / 255.0f) * am_scale[blk >> 8] + am_off[0];
        ivec4 c0 = *(const ivec4*)(codes + base);
        ivec4 c1 = *(const ivec4*)(codes + base + 4);
        unsigned short r[8];
        r[0] = f2bf(nf4[c0.x & 15] * absmax);
        r[1] = f2bf(nf4[c0.y & 15] * absmax);
        r[2] = f2bf(nf4[c0.z & 15] * absmax);
        r[3] = f2bf(nf4[c0.w & 15] * absmax);
        r[4] = f2bf(nf4[c1.x & 15] * absmax);
        r[5] = f2bf(nf4[c1.y & 15] * absmax);
        r[6] = f2bf(nf4[c1.z & 15] * absmax);
        r[7] = f2bf(nf4[c1.w & 15] * absmax);
        *(uvec4*)(wb + base) = *(const uvec4*)r;
    }
}

// ---------------- 256x256 bf16 MFMA GEMM, software-pipelined reads ----------------
//
// 512 threads = 8 waves (2M x 4N), per-wave 128x64 output, mfma 16x16x32.
// LDS: 4-buffer ring per operand (buf = 256x32 bf16 = 16 KiB) -> 128 KiB.
//
// Region t (one K-tile):
//   stage tile t+3 (4 global_load_lds)          // VMEM, 3 tiles in flight
//   ds_read frags of tile t+1 -> F_next (12)    // DS, flies UNDER this tile's MFMA
//   s_waitcnt lgkmcnt(12)                       // counted: waits only last region's
//                                               // 12 reads (F_cur); new 12 keep flying
//   sched_barrier; setprio(1); 32 MFMA on F_cur; setprio(0)
//   s_waitcnt vmcnt(4)                          // tile t+2 globally retired at barrier
//   s_barrier
//
// Ledger (verified): at start of region u, outstanding stages = {u+2} (4 loads);
// +stage(u+3) = 8; vmcnt(4) retires u+2.  So at the barrier ending region u-1,
// every thread's tile-(u+1) staging is retired -> reads(u+1) at region-u start are
// race-free (FIFO vmcnt + barrier join).  WAR: stage(u+4)->buf u&3 issues one full
// barrier after buf u's last ds_reads drained (their lgkmcnt(12) precedes MFMA(u)
// which precedes barrier(u)).  Fragments double-buffered in two NAMED register
// sets (static indexing only), alternated by unroll parity.
//
// LDS swizzle (unchanged, 0 conflicts measured): slot (row,c) holds global k-chunk
// c ^ ((row>>1)&3); staging pre-swizzles the per-lane GLOBAL source chunk.
__device__ inline void gld_lds16(const void* g, void* l) {
    __builtin_amdgcn_global_load_lds((__attribute__((address_space(1))) void*)g,
                                     (__attribute__((address_space(3))) void*)l,
                                     16, 0, 0);
}

__global__ __launch_bounds__(512, 2) void gemm_bt(const unsigned short* __restrict__ A,
                                                  const unsigned short* __restrict__ B,
                                                  const float* __restrict__ bias,
                                                  float* __restrict__ C,
                                                  int M, int N, int K) {
    __shared__ __attribute__((aligned(16))) unsigned short lA[4][BM * BK];
    __shared__ __attribute__((aligned(16))) unsigned short lB[4][BN * BK];

    const int tid  = threadIdx.x;
    const int wave = tid >> 6;
    const int lane = tid & 63;

    // Bijective XCD swizzle: XCD owns bm in {xcd, xcd+8, ...}; all XCDs walk
    // bn 0..15 in lockstep (A panels L2-hot per XCD, B panels L3-shared).
    const int orig = (int)blockIdx.x;
    const int xcd = orig & 7;
    const int idx = orig >> 3;                 // 0..63
    const int bm = ((idx >> 4) << 3) + xcd;    // 0..31
    const int bn = idx & 15;                   // 0..15

    const int wm = (wave >> 2) * 128;
    const int wn = (wave & 3) * 64;

    // Staging: thread t owns 16B slots t and t+512 (rows tid>>2 and +128, same
    // chunk col); source chunk pre-swizzled: gch = (t&3) ^ ((t>>3)&3).
    const int srow = tid >> 2;
    const int gch  = (tid & 3) ^ ((tid >> 3) & 3);
    const unsigned short* sA0 = A + (size_t)(bm * BM + srow) * K + gch * 8;
    const unsigned short* sA1 = sA0 + (size_t)128 * K;
    const unsigned short* sB0 = B + (size_t)(bn * BN + srow) * K + gch * 8;
    const unsigned short* sB1 = sB0 + (size_t)128 * K;

    // Fragment read offsets: row = w? + f*16 + (lane&15), k-chunk = lane>>4,
    // stored at chunk (lane>>4) ^ ((lane>>1)&3)  (swizzle dep only on row&7).
    const int cslot = (lane >> 4) ^ ((lane >> 1) & 3);
    const int aoff = (wm + (lane & 15)) * BK + cslot * 8;
    const int boff = (wn + (lane & 15)) * BK + cslot * 8;

    fvec4 acc[8][4];
#pragma unroll
    for (int m = 0; m < 8; ++m)
#pragma unroll
        for (int n = 0; n < 4; ++n)
#pragma unroll
            for (int r = 0; r < 4; ++r) acc[m][n][r] = 0.0f;

    // Two named fragment register sets (rule #20: static indexing only).
    bf16x8 fa0[8], fb0[4], fa1[8], fb1[4];

    // ---- prologue: issue tiles 0,1,2; vmcnt(4) retires tiles 0,1; read frags(0) ----
#pragma unroll
    for (int pt = 0; pt < 3; ++pt) {
        const int kb = pt * BK;
        gld_lds16(sA0 + kb, &lA[pt][tid * 8]);
        gld_lds16(sA1 + kb, &lA[pt][(tid + 512) * 8]);
        gld_lds16(sB0 + kb, &lB[pt][tid * 8]);
        gld_lds16(sB1 + kb, &lB[pt][(tid + 512) * 8]);
    }
    asm volatile("s_waitcnt vmcnt(4)" ::: "memory");
    __builtin_amdgcn_s_barrier();
#pragma unroll
    for (int m = 0; m < 8; ++m) fa0[m] = *(const bf16x8*)(&lA[0][0] + aoff + m * 512);
#pragma unroll
    for (int n = 0; n < 4; ++n) fb0[n] = *(const bf16x8*)(&lB[0][0] + boff + n * 512);

    // ---- region macro: tile t0+J computes F_cur, reads tile t0+J+1 into F_next ----
#define REGION(J, FAc, FBc, FAn, FBn)                                                  \
    do {                                                                               \
        constexpr int SBUF = ((J) + 3) & 3;                                            \
        constexpr int RBUF = ((J) + 1) & 3;                                            \
        gld_lds16(pA0 + (J) * BK, &lA[SBUF][tid * 8]);                                 \
        gld_lds16(pA1 + (J) * BK, &lA[SBUF][(tid + 512) * 8]);                         \
        gld_lds16(pB0 + (J) * BK, &lB[SBUF][tid * 8]);                                 \
        gld_lds16(pB1 + (J) * BK, &lB[SBUF][(tid + 512) * 8]);                         \
        _Pragma("unroll") for (int m = 0; m < 8; ++m)                                  \
            FAn[m] = *(const bf16x8*)(&lA[RBUF][0] + aoff + m * 512);                  \
        _Pragma("unroll") for (int n = 0; n < 4; ++n)                                  \
            FBn[n] = *(const bf16x8*)(&lB[RBUF][0] + boff + n * 512);                  \
        asm volatile("s_waitcnt lgkmcnt(12)" ::: "memory");                            \
        __builtin_amdgcn_sched_barrier(0);                                             \
        __builtin_amdgcn_s_setprio(1);                                                 \
        _Pragma("unroll") for (int m = 0; m < 8; ++m)                                  \
            _Pragma("unroll") for (int n = 0; n < 4; ++n)                              \
                acc[m][n] = __builtin_amdgcn_mfma_f32_16x16x32_bf16(FAc[m], FBc[n], acc[m][n], 0, 0, 0); \
        __builtin_amdgcn_s_setprio(0);                                                 \
        asm volatile("s_waitcnt vmcnt(4)" ::: "memory");                               \
        __builtin_amdgcn_s_barrier();                                                  \
    } while (0)

    // ---- uniform regions 0..123 (stage tiles 3..126), unrolled x4 ----
    {
        const unsigned short* pA0 = sA0 + 3 * BK;
        const unsigned short* pA1 = sA1 + 3 * BK;
        const unsigned short* pB0 = sB0 + 3 * BK;
        const unsigned short* pB1 = sB1 + 3 * BK;
        for (int t0 = 0; t0 < NT - 4; t0 += 4) {
            REGION(0, fa0, fb0, fa1, fb1);
            REGION(1, fa1, fb1, fa0, fb0);
            REGION(2, fa0, fb0, fa1, fb1);
            REGION(3, fa1, fb1, fa0, fb0);
            pA0 += 4 * BK; pA1 += 4 * BK; pB0 += 4 * BK; pB1 += 4 * BK;
        }
    }

    // ---- tail: t = 124..127 (pointers sit at tile 127 for J=0) ----
    {
        const unsigned short* pA0 = sA0 + 127 * BK;
        const unsigned short* pA1 = sA1 + 127 * BK;
        const unsigned short* pB0 = sB0 + 127 * BK;
        const unsigned short* pB1 = sB1 + 127 * BK;

        // t=124: stage 127 (buf 3); reads(125 -> buf1 -> F1); MFMA F0; vmcnt(4)
        gld_lds16(pA0, &lA[3][tid * 8]);
        gld_lds16(pA1, &lA[3][(tid + 512) * 8]);
        gld_lds16(pB0, &lB[3][tid * 8]);
        gld_lds16(pB1, &lB[3][(tid + 512) * 8]);
#pragma unroll
        for (int m = 0; m < 8; ++m) fa1[m] = *(const bf16x8*)(&lA[1][0] + aoff + m * 512);
#pragma unroll
        for (int n = 0; n < 4; ++n) fb1[n] = *(const bf16x8*)(&lB[1][0] + boff + n * 512);
        asm volatile("s_waitcnt lgkmcnt(12)" ::: "memory");
        __builtin_amdgcn_sched_barrier(0);
        __builtin_amdgcn_s_setprio(1);
#pragma unroll
        for (int m = 0; m < 8; ++m)
#pragma unroll
            for (int n = 0; n < 4; ++n)
                acc[m][n] = __builtin_amdgcn_mfma_f32_16x16x32_bf16(fa0[m], fb0[n], acc[m][n], 0, 0, 0);
        __builtin_amdgcn_s_setprio(0);
        asm volatile("s_waitcnt vmcnt(4)" ::: "memory");
        __builtin_amdgcn_s_barrier();

        // t=125: reads(126 -> buf2 -> F0); MFMA F1; vmcnt(0) (tile 127 retired)
#pragma unroll
        for (int m = 0; m < 8; ++m) fa0[m] = *(const bf16x8*)(&lA[2][0] + aoff + m * 512);
#pragma unroll
        for (int n = 0; n < 4; ++n) fb0[n] = *(const bf16x8*)(&lB[2][0] + boff + n * 512);
        asm volatile("s_waitcnt lgkmcnt(12)" ::: "memory");
        __builtin_amdgcn_sched_barrier(0);
        __builtin_amdgcn_s_setprio(1);
#pragma unroll
        for (int m = 0; m < 8; ++m)
#pragma unroll
            for (int n = 0; n < 4; ++n)
                acc[m][n] = __builtin_amdgcn_mfma_f32_16x16x32_bf16(fa1[m], fb1[n], acc[m][n], 0, 0, 0);
        __builtin_amdgcn_s_setprio(0);
        asm volatile("s_waitcnt vmcnt(0)" ::: "memory");
        __builtin_amdgcn_s_barrier();

        // t=126: reads(127 -> buf3 -> F1); MFMA F0; barrier
#pragma unroll
        for (int m = 0; m < 8; ++m) fa1[m] = *(const bf16x8*)(&lA[3][0] + aoff + m * 512);
#pragma unroll
        for (int n = 0; n < 4; ++n) fb1[n] = *(const bf16x8*)(&lB[3][0] + boff + n * 512);
        asm volatile("s_waitcnt lgkmcnt(12)" ::: "memory");
        __builtin_amdgcn_sched_barrier(0);
        __builtin_amdgcn_s_setprio(1);
#pragma unroll
        for (int m = 0; m < 8; ++m)
#pragma unroll
            for (int n = 0; n < 4; ++n)
                acc[m][n] = __builtin_amdgcn_mfma_f32_16x16x32_bf16(fa0[m], fb0[n], acc[m][n], 0, 0, 0);
        __builtin_amdgcn_s_setprio(0);
        __builtin_amdgcn_s_barrier();

        // t=127: MFMA F1
        asm volatile("s_waitcnt lgkmcnt(0)" ::: "memory");
        __builtin_amdgcn_sched_barrier(0);
        __builtin_amdgcn_s_setprio(1);
#pragma unroll
        for (int m = 0; m < 8; ++m)
#pragma unroll
            for (int n = 0; n < 4; ++n)
                acc[m][n] = __builtin_amdgcn_mfma_f32_16x16x32_bf16(fa1[m], fb1[n], acc[m][n], 0, 0, 0);
        __builtin_amdgcn_s_setprio(0);
    }

    // ---- epilogue: C/D 16x16 layout col = lane&15, row = (lane>>4)*4 + r ----
    const int col0 = bn * BN + wn + (lane & 15);
    const int row0 = bm * BM + wm + ((lane >> 4) << 2);
#pragma unroll
    for (int n = 0; n < 4; ++n) {
        const float bvs = bias[col0 + n * 16];
#pragma unroll
        for (int m = 0; m < 8; ++m) {
            float* cp = C + (size_t)(row0 + m * 16) * N + col0 + n * 16;
#pragma unroll
            for (int r = 0; r < 4; ++r)
                __builtin_nontemporal_store(acc[m][n][r] + bvs, cp + (size_t)r * N);
        }
    }
}

extern "C" void kernel_launch(void* const* d_in, const int* in_sizes, int n_in,
                              void* d_out, int out_size, void* d_ws, size_t ws_size,
                              hipStream_t stream) {
    const float* x        = (const float*)d_in[0];
    const int*   w_codes  = (const int*)d_in[1];
    const int*   am_codes = (const int*)d_in[2];
    const float* am_scale = (const float*)d_in[3];
    const float* am_off   = (const float*)d_in[4];
    const float* bias     = (const float*)d_in[5];
    float* out = (float*)d_out;

    const int M = DIM_M, N = DIM_N, K = DIM_K;

    // workspace: xb (M*K bf16 = 64 MB) | wb (N*K bf16 = 32 MB)
    unsigned short* xb = (unsigned short*)d_ws;
    unsigned short* wb = xb + (size_t)M * K;

    {
        int xcv_blocks = (int)(((size_t)M * K) / 8 / 256);   // 16384
        int wdq_blocks = (int)(((size_t)N * K) / 8 / 256);   // 8192
        prep_kernel<<<xcv_blocks + wdq_blocks, 256, 0, stream>>>(
            x, xb, w_codes, am_codes, am_scale, am_off, wb, xcv_blocks);
    }
    {
        dim3 grid((M / BM) * (N / BN));   // 512 one-dim; XCD swizzle in-kernel
        gemm_bt<<<grid, 512, 0, stream>>>(xb, wb, bias, out, M, N, K);
    }
}